// Round 5
// baseline (99.944 us; speedup 1.0000x reference)
//
#include <hip/hip_runtime.h>
#include <math.h>

#define MITEMS 4  // priors per thread in match kernel (keeps VGPR ~124, no spill)
#define LB 32     // blocks per batch for loss/hist/sum kernels

// ---------------------------------------------------------------------------
// ws layout (zeroed by one hipMemsetAsync up to hist2 end):
//   double pconf[B], ploc[B], phard[B]      : per-batch partial sums
//   int    n_pos[B]
//   u64    prior_fo[B*n_obj]                : packed (iou_bits<<32)|(0xFFFFFFFF-p)
//   u32    hist0[B][4096], hist1[B][4096], hist2[B][256]
//   float  conf_neg[B*P]
//   u8     best_u8[B*P]                     : bit7 = (iou>=0.5), bits0-6 = obj
//   u64    part_fo[B*NBLK*NOBJ]             : per-block partial argmax (no atomics)
// ---------------------------------------------------------------------------

template <int NOBJ, bool FULL>
__global__ __launch_bounds__(256) void mbl_match(
    const float* __restrict__ boxes, const float* __restrict__ priors,
    unsigned long long* __restrict__ part_fo, unsigned char* __restrict__ best_u8,
    int P, int n_obj) {
  const int b = blockIdx.y;
  const int tid = threadIdx.x;
  __shared__ float4 s_box[NOBJ][2];  // {lo0,lo1,lo2,hi0},{hi1,hi2,vol,0}
  __shared__ unsigned long long s_part[4][NOBJ];
  for (int i = tid; i < NOBJ; i += 256) {
    float4 v0, v1;
    if (i < n_obj) {
      const float* bx = boxes + ((size_t)b * n_obj + i) * 6;
      const float l0 = bx[0], l1 = bx[1], l2 = bx[2];
      const float h0 = bx[3], h1 = bx[4], h2 = bx[5];
      v0 = make_float4(l0, l1, l2, h0);
      v1 = make_float4(h1, h2, ((h0 - l0) * (h1 - l1)) * (h2 - l2), 0.f);
    } else {  // dummy object: iou 0 vs everything
      v0 = make_float4(3e18f, 3e18f, 3e18f, 1e18f);
      v1 = make_float4(1e18f, 1e18f, 0.f, 0.f);
    }
    s_box[i][0] = v0;
    s_box[i][1] = v1;
  }
  __syncthreads();

  float lo0[MITEMS], lo1[MITEMS], lo2[MITEMS], hi0[MITEMS], hi1[MITEMS],
      hi2[MITEMS], vb[MITEMS];
  unsigned invp[MITEMS];
  const int base = blockIdx.x * (256 * MITEMS);
#pragma unroll
  for (int k = 0; k < MITEMS; ++k) {
    const int p = base + k * 256 + tid;
    if (FULL || p < P) {
      const float2 q0 = *(const float2*)(priors + (size_t)p * 6);
      const float2 q1 = *(const float2*)(priors + (size_t)p * 6 + 2);
      const float2 q2 = *(const float2*)(priors + (size_t)p * 6 + 4);
      lo0[k] = q0.x - q1.y * 0.5f; hi0[k] = q0.x + q1.y * 0.5f;
      lo1[k] = q0.y - q2.x * 0.5f; hi1[k] = q0.y + q2.x * 0.5f;
      lo2[k] = q1.x - q2.y * 0.5f; hi2[k] = q1.x + q2.y * 0.5f;
      vb[k] = (q1.y * q2.x) * q2.y;  // sizes product == box volume
      invp[k] = 0xFFFFFFFFu - (unsigned)p;
    } else {  // dummy prior: iou 0, never wins argmax (invp 0)
      lo0[k] = lo1[k] = lo2[k] = 3e18f;
      hi0[k] = hi1[k] = hi2[k] = 3e18f;
      vb[k] = 0.f;
      invp[k] = 0u;
    }
  }

  float piou[NOBJ];
  unsigned pinv[NOBJ];
#pragma unroll
  for (int o = 0; o < NOBJ; ++o) { piou[o] = -1.0f; pinv[o] = 0u; }
  float bv[MITEMS];
  int bo[MITEMS];
#pragma unroll
  for (int k = 0; k < MITEMS; ++k) { bv[k] = -1.0f; bo[k] = 0; }

#pragma unroll
  for (int o = 0; o < NOBJ; ++o) {
    const float4 c0 = s_box[o][0];
    const float4 c1 = s_box[o][1];
#pragma unroll
    for (int k = 0; k < MITEMS; ++k) {
      const float d0 = fminf(c0.w, hi0[k]) - fmaxf(c0.x, lo0[k]);
      const float d1 = fminf(c1.x, hi1[k]) - fmaxf(c0.y, lo1[k]);
      const float d2 = fminf(c1.y, hi2[k]) - fmaxf(c0.z, lo2[k]);
      const float inter = (fmaxf(d0, 0.f) * fmaxf(d1, 0.f)) * fmaxf(d2, 0.f);
      const float un = (c1.z + vb[k]) - inter;
      const float iou = inter * __builtin_amdgcn_rcpf(un);
      if (iou > bv[k]) { bv[k] = iou; bo[k] = o; }  // first-occurrence argmax
      if (iou > piou[o]) { piou[o] = iou; pinv[o] = invp[k]; }
    }
  }

  const int lane = tid & 63, wv = tid >> 6;
#pragma unroll
  for (int o = 0; o < NOBJ; ++o) {
    unsigned long long v =
        (piou[o] < 0.f)
            ? 0ULL
            : (((unsigned long long)__float_as_uint(piou[o]) << 32) | pinv[o]);
    for (int off = 1; off < 64; off <<= 1) {
      const unsigned long long w = __shfl_xor(v, off, 64);
      if (w > v) v = w;
    }
    if (lane == 0) s_part[wv][o] = v;
  }
  __syncthreads();
  if (tid < NOBJ) {
    unsigned long long v = s_part[0][tid];
    for (int w = 1; w < 4; ++w)
      if (s_part[w][tid] > v) v = s_part[w][tid];
    // plain store to private slot — no atomic contention
    part_fo[((size_t)b * gridDim.x + blockIdx.x) * NOBJ + tid] = v;
  }
#pragma unroll
  for (int k = 0; k < MITEMS; ++k) {
    const int p = base + k * 256 + tid;
    if (FULL || p < P)
      best_u8[(size_t)b * P + p] =
          (unsigned char)((unsigned)bo[k] | (bv[k] >= 0.5f ? 0x80u : 0u));
  }
}

// Reduce per-block partials -> prior_fo[b][o]. One block per batch.
__global__ __launch_bounds__(256) void mbl_reduce_fo(
    const unsigned long long* __restrict__ part_fo,
    unsigned long long* __restrict__ prior_fo, int nblk, int n_obj, int nobjT) {
  const int b = blockIdx.x;
  const int tid = threadIdx.x;
  const int sub = tid & 15;
  for (int o0 = 0; o0 < n_obj; o0 += 16) {
    const int o = o0 + (tid >> 4);
    unsigned long long v = 0ULL;
    if (o < n_obj) {
      const unsigned long long* base = part_fo + (size_t)b * nblk * nobjT + o;
      for (int i = sub; i < nblk; i += 16) {
        const unsigned long long x = base[(size_t)i * nobjT];
        if (x > v) v = x;
      }
    }
    // xor-butterfly within each 16-lane group (stays inside the group)
#pragma unroll
    for (int off = 1; off < 16; off <<= 1) {
      const unsigned long long w = __shfl_xor(v, off, 64);
      if (w > v) v = w;
    }
    if (sub == 0 && o < n_obj) prior_fo[(size_t)b * n_obj + o] = v;
  }
}

// Phase B: labels, CE, loc L1, conf_neg + fused 12-bit round-0 histogram.
template <int CC>
__global__ __launch_bounds__(256) void mbl_loss(
    const float* __restrict__ locs, const float* __restrict__ scores,
    const float* __restrict__ boxes, const int* __restrict__ labels,
    const float* __restrict__ priors, const unsigned long long* __restrict__ prior_fo,
    const unsigned char* __restrict__ best_u8, float* __restrict__ conf_neg,
    unsigned* __restrict__ hist0, int* __restrict__ n_pos,
    double* __restrict__ pconf, double* __restrict__ ploc, int P, int n_obj, int C) {
  const int b = blockIdx.y;
  const int tid = threadIdx.x;
  __shared__ float s_box[64][6];
  __shared__ int s_lab[64];
  __shared__ unsigned s_fo[64];
  __shared__ unsigned s_hist[4096];
  for (int i = tid; i < 4096; i += 256) s_hist[i] = 0u;
  for (int i = tid; i < n_obj * 6; i += 256)
    s_box[i / 6][i % 6] = boxes[(size_t)b * n_obj * 6 + i];
  for (int i = tid; i < n_obj; i += 256) {
    s_lab[i] = labels[(size_t)b * n_obj + i];
    s_fo[i] = 0xFFFFFFFFu - (unsigned)(prior_fo[(size_t)b * n_obj + i] & 0xFFFFFFFFull);
  }
  __syncthreads();

  unsigned fo_r[16];
  const bool small_obj = (n_obj <= 16);
  if (small_obj) {
#pragma unroll
    for (int o = 0; o < 16; ++o) fo_r[o] = (o < n_obj) ? s_fo[o] : 0xFFFFFFFEu;
  }

  const int chunk = (P + gridDim.x - 1) / gridDim.x;
  const int start = blockIdx.x * chunk;
  const int end = min(start + chunk, P);
  int np_l = 0;
  double cf_l = 0.0, lc_l = 0.0;
  for (int p = start + tid; p < end; p += 256) {
    const unsigned char bp = best_u8[(size_t)b * P + p];
    int obj = bp & 0x7F;
    int posf = bp >> 7;
    if (small_obj) {
#pragma unroll
      for (int o = 0; o < 16; ++o)
        if (fo_r[o] == (unsigned)p) { obj = o; posf = 1; }  // last wins
    } else {
      for (int o = 0; o < n_obj; ++o)
        if (s_fo[o] == (unsigned)p) { obj = o; posf = 1; }
    }
    const int lab = posf ? s_lab[obj] : 0;

    float conf;
    if (CC == 2) {
      const float2 sc = *(const float2*)(scores + ((size_t)b * P + p) * 2);
      const float m = fmaxf(sc.x, sc.y);
      conf = (lab < 0) ? 0.f
                       : (m + __logf(__expf(sc.x - m) + __expf(sc.y - m)) -
                          ((lab == 0) ? sc.x : sc.y));
    } else {
      const float* sp = scores + ((size_t)b * P + p) * C;
      float m = sp[0];
      for (int c = 1; c < C; ++c) m = fmaxf(m, sp[c]);
      float se = 0.f;
      for (int c = 0; c < C; ++c) se += __expf(sp[c] - m);
      conf = (lab < 0) ? 0.f : (m + __logf(se) - sp[lab]);
    }

    float cn = conf;
    if (lab > 0) {
      np_l++;
      cf_l += (double)conf;
      const float* pr = priors + (size_t)p * 6;
      const float* pl = locs + ((size_t)b * P + p) * 6;
      float ls = 0.f;
      for (int i = 0; i < 3; ++i) {
        const float c0 = (s_box[obj][i] + s_box[obj][i + 3]) * 0.5f;
        const float szb = s_box[obj][i + 3] - s_box[obj][i];
        const float g = (c0 - pr[i]) / (pr[i + 3] / 10.0f);
        const float g2 = logf(szb / pr[i + 3]) * 5.0f;
        ls += fabsf(pl[i] - g) + fabsf(pl[i + 3] - g2);
      }
      lc_l += (double)ls;
      cn = 0.f;
    }
    conf_neg[(size_t)b * P + p] = cn;
    atomicAdd(&s_hist[__float_as_uint(cn) >> 20], 1u);
  }

  __shared__ int r_np[256];
  __shared__ double r_c[256];
  __shared__ double r_l[256];
  r_np[tid] = np_l;
  r_c[tid] = cf_l;
  r_l[tid] = lc_l;
  __syncthreads();
  for (int s = 128; s > 0; s >>= 1) {
    if (tid < s) {
      r_np[tid] += r_np[tid + s];
      r_c[tid] += r_c[tid + s];
      r_l[tid] += r_l[tid + s];
    }
    __syncthreads();
  }
  if (tid == 0 && r_np[0] > 0) {
    atomicAdd(&n_pos[b], r_np[0]);
    atomicAdd(&pconf[b], r_c[0]);
    atomicAdd(&ploc[b], r_l[0]);
  }
  for (int i = tid; i < 4096; i += 256)
    if (s_hist[i]) atomicAdd(&hist0[(size_t)b * 4096 + i], s_hist[i]);
}

// Cooperative block-wide radix select over BINS bins (descending cumulative).
template <int BINS>
__device__ void block_select(const unsigned* __restrict__ h, int remk,
                             unsigned* s_scan, int* s_out, unsigned* sel,
                             int* remk_o) {
  constexpr int BPT = BINS / 256;
  const int t = threadIdx.x;
  if (t == 0) { s_out[0] = BINS - 1; s_out[1] = 0; }  // default: remk<=0 sentinel
  unsigned mb[BPT];
  unsigned s = 0;
#pragma unroll
  for (int i = 0; i < BPT; ++i) { mb[i] = h[t * BPT + i]; s += mb[i]; }
  unsigned incl = s;
  s_scan[t] = incl;
  __syncthreads();
  for (int off = 1; off < 256; off <<= 1) {
    const unsigned add = (t >= off) ? s_scan[t - off] : 0u;
    __syncthreads();
    incl += add;
    s_scan[t] = incl;
    __syncthreads();
  }
  const unsigned total = s_scan[255];
  const unsigned R = total - incl;  // count in bins above this thread's range
  if (remk > 0 && R < (unsigned)remk && R + s >= (unsigned)remk) {
    unsigned acc = R;
    int sel_i = t * BPT, rk = 0;
    bool done = false;
#pragma unroll
    for (int i = BPT - 1; i >= 0; --i) {
      if (!done && acc + mb[i] >= (unsigned)remk) {
        sel_i = t * BPT + i;
        rk = remk - (int)acc;
        done = true;
      }
      if (!done) acc += mb[i];
    }
    s_out[0] = sel_i;
    s_out[1] = rk;
  }
  __syncthreads();
  *sel = (unsigned)s_out[0];
  *remk_o = s_out[1];
  __syncthreads();
}

__global__ __launch_bounds__(256) void mbl_hist1(
    const float* __restrict__ conf_neg, const int* __restrict__ n_pos,
    const unsigned* __restrict__ hist0, unsigned* __restrict__ hist1, int P) {
  const int b = blockIdx.y;
  const int tid = threadIdx.x;
  __shared__ unsigned s_scan[256];
  __shared__ int s_out[2];
  __shared__ unsigned s_hist[4096];
  int K = 3 * n_pos[b];
  if (K > P) K = P;
  unsigned sel0;
  int rem0;
  block_select<4096>(hist0 + (size_t)b * 4096, K, s_scan, s_out, &sel0, &rem0);
  for (int i = tid; i < 4096; i += 256) s_hist[i] = 0u;
  __syncthreads();
  const float* row = conf_neg + (size_t)b * P;
  const int n4 = P >> 2;
  const int per = (n4 + (int)gridDim.x - 1) / (int)gridDim.x;
  const int s4 = blockIdx.x * per, e4 = min(s4 + per, n4);
  for (int i = s4 + tid; i < e4; i += 256) {
    const float4 v = ((const float4*)row)[i];
    unsigned u;
    u = __float_as_uint(v.x); if ((u >> 20) == sel0) atomicAdd(&s_hist[(u >> 8) & 4095u], 1u);
    u = __float_as_uint(v.y); if ((u >> 20) == sel0) atomicAdd(&s_hist[(u >> 8) & 4095u], 1u);
    u = __float_as_uint(v.z); if ((u >> 20) == sel0) atomicAdd(&s_hist[(u >> 8) & 4095u], 1u);
    u = __float_as_uint(v.w); if ((u >> 20) == sel0) atomicAdd(&s_hist[(u >> 8) & 4095u], 1u);
  }
  if (blockIdx.x == 0)
    for (int p = (n4 << 2) + tid; p < P; p += 256) {
      const unsigned u = __float_as_uint(row[p]);
      if ((u >> 20) == sel0) atomicAdd(&s_hist[(u >> 8) & 4095u], 1u);
    }
  __syncthreads();
  for (int i = tid; i < 4096; i += 256)
    if (s_hist[i]) atomicAdd(&hist1[(size_t)b * 4096 + i], s_hist[i]);
}

__global__ __launch_bounds__(256) void mbl_hist2(
    const float* __restrict__ conf_neg, const int* __restrict__ n_pos,
    const unsigned* __restrict__ hist0, const unsigned* __restrict__ hist1,
    unsigned* __restrict__ hist2, int P) {
  const int b = blockIdx.y;
  const int tid = threadIdx.x;
  __shared__ unsigned s_scan[256];
  __shared__ int s_out[2];
  __shared__ unsigned s_hist[256];
  int K = 3 * n_pos[b];
  if (K > P) K = P;
  unsigned sel0, sel1;
  int rem0, rem1;
  block_select<4096>(hist0 + (size_t)b * 4096, K, s_scan, s_out, &sel0, &rem0);
  block_select<4096>(hist1 + (size_t)b * 4096, rem0, s_scan, s_out, &sel1, &rem1);
  s_hist[tid] = 0u;
  __syncthreads();
  const unsigned pref20 = (sel0 << 12) | sel1;
  const float* row = conf_neg + (size_t)b * P;
  const int n4 = P >> 2;
  const int per = (n4 + (int)gridDim.x - 1) / (int)gridDim.x;
  const int s4 = blockIdx.x * per, e4 = min(s4 + per, n4);
  for (int i = s4 + tid; i < e4; i += 256) {
    const float4 v = ((const float4*)row)[i];
    unsigned u;
    u = __float_as_uint(v.x); if ((u >> 8) == pref20) atomicAdd(&s_hist[u & 255u], 1u);
    u = __float_as_uint(v.y); if ((u >> 8) == pref20) atomicAdd(&s_hist[u & 255u], 1u);
    u = __float_as_uint(v.z); if ((u >> 8) == pref20) atomicAdd(&s_hist[u & 255u], 1u);
    u = __float_as_uint(v.w); if ((u >> 8) == pref20) atomicAdd(&s_hist[u & 255u], 1u);
  }
  if (blockIdx.x == 0)
    for (int p = (n4 << 2) + tid; p < P; p += 256) {
      const unsigned u = __float_as_uint(row[p]);
      if ((u >> 8) == pref20) atomicAdd(&s_hist[u & 255u], 1u);
    }
  __syncthreads();
  if (s_hist[tid]) atomicAdd(&hist2[(size_t)b * 256 + tid], s_hist[tid]);
}

__global__ __launch_bounds__(256) void mbl_sum(
    const float* __restrict__ conf_neg, const int* __restrict__ n_pos,
    const unsigned* __restrict__ hist0, const unsigned* __restrict__ hist1,
    const unsigned* __restrict__ hist2, double* __restrict__ phard, int P) {
  const int b = blockIdx.y;
  const int tid = threadIdx.x;
  __shared__ unsigned s_scan[256];
  __shared__ int s_out[2];
  int K = 3 * n_pos[b];
  if (K > P) K = P;
  unsigned sel0, sel1, sel2;
  int rem0, rem1, rem2;
  block_select<4096>(hist0 + (size_t)b * 4096, K, s_scan, s_out, &sel0, &rem0);
  block_select<4096>(hist1 + (size_t)b * 4096, rem0, s_scan, s_out, &sel1, &rem1);
  block_select<256>(hist2 + (size_t)b * 256, rem1, s_scan, s_out, &sel2, &rem2);
  const unsigned tbits = (sel0 << 20) | (sel1 << 8) | sel2;
  const float* row = conf_neg + (size_t)b * P;
  const int n4 = P >> 2;
  const int per = (n4 + (int)gridDim.x - 1) / (int)gridDim.x;
  const int s4 = blockIdx.x * per, e4 = min(s4 + per, n4);
  double local = 0.0;
  for (int i = s4 + tid; i < e4; i += 256) {
    const float4 v = ((const float4*)row)[i];
    if (__float_as_uint(v.x) > tbits) local += (double)v.x;
    if (__float_as_uint(v.y) > tbits) local += (double)v.y;
    if (__float_as_uint(v.z) > tbits) local += (double)v.z;
    if (__float_as_uint(v.w) > tbits) local += (double)v.w;
  }
  if (blockIdx.x == 0)
    for (int p = (n4 << 2) + tid; p < P; p += 256) {
      const float v = row[p];
      if (__float_as_uint(v) > tbits) local += (double)v;
    }
  __shared__ double red[256];
  red[tid] = local;
  __syncthreads();
  for (int s = 128; s > 0; s >>= 1) {
    if (tid < s) red[tid] += red[tid + s];
    __syncthreads();
  }
  if (tid == 0) {
    double v = red[0];
    if (blockIdx.x == 0 && rem2 > 0)
      v += (double)rem2 * (double)__uint_as_float(tbits);
    if (v != 0.0) atomicAdd(&phard[b], v);
  }
}

__global__ void mbl_finalize(const double* __restrict__ pconf,
                             const double* __restrict__ ploc,
                             const double* __restrict__ phard,
                             const int* __restrict__ n_pos, int B,
                             float* __restrict__ out) {
  if (threadIdx.x == 0 && blockIdx.x == 0) {
    double tp = 0.0, cs = 0.0, ls = 0.0, hs = 0.0;
    for (int b = 0; b < B; ++b) {
      tp += (double)n_pos[b];
      cs += pconf[b];
      ls += ploc[b];
      hs += phard[b];
    }
    out[0] = (float)((hs + cs) / tp);
    out[1] = (float)(ls / (tp * 6.0));
  }
}

extern "C" void kernel_launch(void* const* d_in, const int* in_sizes, int n_in,
                              void* d_out, int out_size, void* d_ws, size_t ws_size,
                              hipStream_t stream) {
  const float* locs = (const float*)d_in[0];
  const float* scores = (const float*)d_in[1];
  const float* boxes = (const float*)d_in[2];
  const int* labels = (const int*)d_in[3];
  const float* priors = (const float*)d_in[4];

  const long long sz_locs = (long long)in_sizes[0];
  const long long sz_scores = (long long)in_sizes[1];
  const long long sz_priors = (long long)in_sizes[4];
  const int P = (int)(sz_priors / 6);
  const int B = (int)(sz_locs / sz_priors);
  const int n_obj = in_sizes[3] / B;
  const int C = (int)(sz_scores * 6 / sz_locs);

  const int tile = 256 * MITEMS;
  const int nblk = (P + tile - 1) / tile;
  const int nobjT = (n_obj <= 16) ? 16 : ((n_obj <= 32) ? 32 : 64);

  char* ws = (char*)d_ws;
  size_t off = 0;
  double* pconf = (double*)(ws + off); off += (size_t)B * 8;
  double* ploc = (double*)(ws + off); off += (size_t)B * 8;
  double* phard = (double*)(ws + off); off += (size_t)B * 8;
  int* n_pos = (int*)(ws + off); off += ((size_t)B * 4 + 15) & ~(size_t)15;
  unsigned long long* prior_fo = (unsigned long long*)(ws + off);
  off += ((size_t)B * n_obj * 8 + 15) & ~(size_t)15;
  unsigned* hist0 = (unsigned*)(ws + off); off += (size_t)B * 4096 * 4;
  unsigned* hist1 = (unsigned*)(ws + off); off += (size_t)B * 4096 * 4;
  unsigned* hist2 = (unsigned*)(ws + off); off += (size_t)B * 256 * 4;
  const size_t zero_bytes = off;
  float* conf_neg = (float*)(ws + off); off += ((size_t)B * P * 4 + 15) & ~(size_t)15;
  unsigned char* best_u8 = (unsigned char*)(ws + off);
  off += ((size_t)B * P + 15) & ~(size_t)15;
  unsigned long long* part_fo = (unsigned long long*)(ws + off);
  off += (size_t)B * nblk * nobjT * 8;
  (void)ws_size;

  hipMemsetAsync(d_ws, 0, zero_bytes, stream);

  const dim3 mgrid(nblk, B);
  const bool full = (P % tile) == 0;
  if (n_obj <= 16) {
    if (full) mbl_match<16, true><<<mgrid, 256, 0, stream>>>(boxes, priors, part_fo, best_u8, P, n_obj);
    else      mbl_match<16, false><<<mgrid, 256, 0, stream>>>(boxes, priors, part_fo, best_u8, P, n_obj);
  } else if (n_obj <= 32) {
    if (full) mbl_match<32, true><<<mgrid, 256, 0, stream>>>(boxes, priors, part_fo, best_u8, P, n_obj);
    else      mbl_match<32, false><<<mgrid, 256, 0, stream>>>(boxes, priors, part_fo, best_u8, P, n_obj);
  } else {
    if (full) mbl_match<64, true><<<mgrid, 256, 0, stream>>>(boxes, priors, part_fo, best_u8, P, n_obj);
    else      mbl_match<64, false><<<mgrid, 256, 0, stream>>>(boxes, priors, part_fo, best_u8, P, n_obj);
  }

  mbl_reduce_fo<<<B, 256, 0, stream>>>(part_fo, prior_fo, nblk, n_obj, nobjT);

  const dim3 lgrid(LB, B);
  if (C == 2)
    mbl_loss<2><<<lgrid, 256, 0, stream>>>(locs, scores, boxes, labels, priors, prior_fo,
                                           best_u8, conf_neg, hist0, n_pos, pconf, ploc,
                                           P, n_obj, C);
  else
    mbl_loss<0><<<lgrid, 256, 0, stream>>>(locs, scores, boxes, labels, priors, prior_fo,
                                           best_u8, conf_neg, hist0, n_pos, pconf, ploc,
                                           P, n_obj, C);

  mbl_hist1<<<lgrid, 256, 0, stream>>>(conf_neg, n_pos, hist0, hist1, P);
  mbl_hist2<<<lgrid, 256, 0, stream>>>(conf_neg, n_pos, hist0, hist1, hist2, P);
  mbl_sum<<<lgrid, 256, 0, stream>>>(conf_neg, n_pos, hist0, hist1, hist2, phard, P);
  mbl_finalize<<<1, 64, 0, stream>>>(pconf, ploc, phard, n_pos, B, (float*)d_out);
}

// Round 6
// 88.597 us; speedup vs baseline: 1.1281x; 1.1281x over previous
//
#include <hip/hip_runtime.h>
#include <math.h>

#define MITEMS 2  // priors per thread in match (low VGPR -> 5+ waves/SIMD)
#define LB 32     // blocks per batch for loss/hist/sum kernels

// ---------------------------------------------------------------------------
// ws layout:
//   double pconf[B], ploc[B], phard[B] ; int n_pos[B] ; u32 counter (+pad)
//   u32    hist0[B][4096], hist1[B][4096]     <- all above zeroed by reduce_fo
//   float  conf_neg[B*P]
//   u8     best_u8[B*P]   : bit7 = positive, bits0-6 = best obj (incl. override)
//   u64    part_fo[B*nblk*NOBJ] : per-block per-object packed (iou_bits<<32)|(~p)
// ---------------------------------------------------------------------------

template <int NOBJ, bool FULL>
__global__ __launch_bounds__(256) void mbl_match(
    const float* __restrict__ boxes, const float* __restrict__ priors,
    unsigned long long* __restrict__ part_fo, unsigned char* __restrict__ best_u8,
    int P, int n_obj) {
  const int b = blockIdx.y;
  const int tid = threadIdx.x;
  __shared__ float4 s_box[NOBJ][2];  // {lo0,lo1,lo2,hi0},{hi1,hi2,vol,0}
  __shared__ unsigned s_iou[8][257];
  __shared__ unsigned s_inv[8][257];
  __shared__ unsigned long long s_red2[8][33];

  for (int i = tid; i < NOBJ; i += 256) {
    float4 v0, v1;
    if (i < n_obj) {
      const float* bx = boxes + ((size_t)b * n_obj + i) * 6;
      const float l0 = bx[0], l1 = bx[1], l2 = bx[2];
      const float h0 = bx[3], h1 = bx[4], h2 = bx[5];
      v0 = make_float4(l0, l1, l2, h0);
      v1 = make_float4(h1, h2, ((h0 - l0) * (h1 - l1)) * (h2 - l2), 0.f);
    } else {  // dummy object: iou 0 vs everything
      v0 = make_float4(3e18f, 3e18f, 3e18f, 1e18f);
      v1 = make_float4(1e18f, 1e18f, 0.f, 0.f);
    }
    s_box[i][0] = v0;
    s_box[i][1] = v1;
  }
  __syncthreads();

  float lo0[MITEMS], lo1[MITEMS], lo2[MITEMS], hi0[MITEMS], hi1[MITEMS],
      hi2[MITEMS], vb[MITEMS];
  unsigned invp[MITEMS];
  const int base = blockIdx.x * (256 * MITEMS);
#pragma unroll
  for (int k = 0; k < MITEMS; ++k) {
    const int p = base + k * 256 + tid;
    if (FULL || p < P) {
      const float2 q0 = *(const float2*)(priors + (size_t)p * 6);
      const float2 q1 = *(const float2*)(priors + (size_t)p * 6 + 2);
      const float2 q2 = *(const float2*)(priors + (size_t)p * 6 + 4);
      lo0[k] = q0.x - q1.y * 0.5f; hi0[k] = q0.x + q1.y * 0.5f;
      lo1[k] = q0.y - q2.x * 0.5f; hi1[k] = q0.y + q2.x * 0.5f;
      lo2[k] = q1.x - q2.y * 0.5f; hi2[k] = q1.x + q2.y * 0.5f;
      vb[k] = (q1.y * q2.x) * q2.y;  // sizes product == box volume
      invp[k] = 0xFFFFFFFFu - (unsigned)p;
    } else {  // dummy prior: iou 0, never wins argmax (invp 0)
      lo0[k] = lo1[k] = lo2[k] = 3e18f;
      hi0[k] = hi1[k] = hi2[k] = 3e18f;
      vb[k] = 0.f;
      invp[k] = 0u;
    }
  }

  float piou[NOBJ];
  unsigned pinv[NOBJ];
#pragma unroll
  for (int o = 0; o < NOBJ; ++o) { piou[o] = -1.0f; pinv[o] = 0u; }
  float bv[MITEMS];
  int bo[MITEMS];
#pragma unroll
  for (int k = 0; k < MITEMS; ++k) { bv[k] = -1.0f; bo[k] = 0; }

#pragma unroll
  for (int o = 0; o < NOBJ; ++o) {
    const float4 c0 = s_box[o][0];
    const float4 c1 = s_box[o][1];
#pragma unroll
    for (int k = 0; k < MITEMS; ++k) {
      const float d0 = fminf(c0.w, hi0[k]) - fmaxf(c0.x, lo0[k]);
      const float d1 = fminf(c1.x, hi1[k]) - fmaxf(c0.y, lo1[k]);
      const float d2 = fminf(c1.y, hi2[k]) - fmaxf(c0.z, lo2[k]);
      const float inter = (fmaxf(d0, 0.f) * fmaxf(d1, 0.f)) * fmaxf(d2, 0.f);
      const float un = (c1.z + vb[k]) - inter;
      const float iou = inter * __builtin_amdgcn_rcpf(un);
      if (iou > bv[k]) { bv[k] = iou; bo[k] = o; }  // first-occurrence argmax
      if (iou > piou[o]) { piou[o] = iou; pinv[o] = invp[k]; }
    }
  }

#pragma unroll
  for (int k = 0; k < MITEMS; ++k) {
    const int p = base + k * 256 + tid;
    if (FULL || p < P)
      best_u8[(size_t)b * P + p] =
          (unsigned char)((unsigned)bo[k] | (bv[k] >= 0.5f ? 0x80u : 0u));
  }

  // Epilogue: per-object block reduction via LDS transpose (8 objects/pass).
  for (int pass = 0; pass < NOBJ / 8; ++pass) {
    if (pass > 0) __syncthreads();
#pragma unroll
    for (int o = 0; o < NOBJ; ++o) {
      if ((o >> 3) == pass) {
        s_iou[o & 7][tid] = __float_as_uint(piou[o]);  // always >= 0 bits
        s_inv[o & 7][tid] = pinv[o];
      }
    }
    __syncthreads();
    const int obj8 = tid >> 5, seg = tid & 31;
    unsigned long long m = 0ULL;
#pragma unroll
    for (int i = 0; i < 8; ++i) {
      const int idx = seg + 32 * i;
      const unsigned long long x =
          ((unsigned long long)s_iou[obj8][idx] << 32) | s_inv[obj8][idx];
      if (x > m) m = x;
    }
    s_red2[obj8][seg] = m;
    __syncthreads();
    if (tid < 8) {
      unsigned long long m2 = 0ULL;
      for (int i = 0; i < 32; ++i) {
        const unsigned long long x = s_red2[tid][i];
        if (x > m2) m2 = x;
      }
      const int o = pass * 8 + tid;
      if (o < n_obj)
        part_fo[((size_t)b * gridDim.x + blockIdx.x) * NOBJ + o] = m2;
    }
  }
}

// Reduce per-block partials, write forced-match override into best_u8.
// Also zeroes the accumulator/hist region (runs between match and loss).
__global__ __launch_bounds__(256) void mbl_reduce_fo(
    const unsigned long long* __restrict__ part_fo,
    unsigned char* __restrict__ best_u8,
    unsigned long long* __restrict__ zero_buf, int zero_words,
    int nblk, int n_obj, int nobjT, int P) {
  const int b = blockIdx.x;
  const int tid = threadIdx.x;
  // zero duty, spread over all B blocks
  {
    const int total = (int)gridDim.x * 256;
    for (int i = b * 256 + tid; i < zero_words; i += total) zero_buf[i] = 0ULL;
  }
  __shared__ unsigned s_win[64];
  const int j = tid & 15;
  for (int o0 = 0; o0 < n_obj; o0 += 16) {
    const int o = o0 + (tid >> 4);
    unsigned long long v = 0ULL;
    if (o < n_obj) {
      const unsigned long long* src = part_fo + (size_t)b * nblk * nobjT + o;
      for (int i = j; i < nblk; i += 16) {
        const unsigned long long x = src[(size_t)i * nobjT];
        if (x > v) v = x;
      }
    }
#pragma unroll
    for (int off = 1; off < 16; off <<= 1) {
      const unsigned long long w = __shfl_xor(v, off, 64);
      if (w > v) v = w;
    }
    if (j == 0 && o < n_obj)
      s_win[o] = 0xFFFFFFFFu - (unsigned)(v & 0xFFFFFFFFull);
  }
  __syncthreads();
  if (tid == 0) {  // ascending o, last wins = numpy .at[].set semantics
    for (int o = 0; o < n_obj; ++o)
      best_u8[(size_t)b * P + s_win[o]] = (unsigned char)(0x80u | (unsigned)o);
  }
}

// Labels, CE, loc L1, conf_neg + fused 12-bit round-0 histogram.
template <int CC>
__global__ __launch_bounds__(256) void mbl_loss(
    const float* __restrict__ locs, const float* __restrict__ scores,
    const float* __restrict__ boxes, const int* __restrict__ labels,
    const float* __restrict__ priors, const unsigned char* __restrict__ best_u8,
    float* __restrict__ conf_neg, unsigned* __restrict__ hist0,
    int* __restrict__ n_pos, double* __restrict__ pconf, double* __restrict__ ploc,
    int P, int n_obj, int C) {
  const int b = blockIdx.y;
  const int tid = threadIdx.x;
  __shared__ float s_box[64][6];
  __shared__ int s_lab[64];
  __shared__ unsigned s_hist[4096];
  for (int i = tid; i < 4096; i += 256) s_hist[i] = 0u;
  for (int i = tid; i < n_obj * 6; i += 256)
    s_box[i / 6][i % 6] = boxes[(size_t)b * n_obj * 6 + i];
  for (int i = tid; i < n_obj; i += 256) s_lab[i] = labels[(size_t)b * n_obj + i];
  __syncthreads();

  const int chunk = (P + gridDim.x - 1) / gridDim.x;
  const int start = blockIdx.x * chunk;
  const int end = min(start + chunk, P);
  int np_l = 0;
  double cf_l = 0.0, lc_l = 0.0;
  for (int p = start + tid; p < end; p += 256) {
    const unsigned char bp = best_u8[(size_t)b * P + p];
    const int obj = bp & 0x7F;
    const int posf = bp >> 7;
    const int lab = posf ? s_lab[obj] : 0;

    float conf;
    if (CC == 2) {
      const float2 sc = *(const float2*)(scores + ((size_t)b * P + p) * 2);
      const float m = fmaxf(sc.x, sc.y);
      conf = (lab < 0) ? 0.f
                       : (m + __logf(__expf(sc.x - m) + __expf(sc.y - m)) -
                          ((lab == 0) ? sc.x : sc.y));
    } else {
      const float* sp = scores + ((size_t)b * P + p) * C;
      float m = sp[0];
      for (int c = 1; c < C; ++c) m = fmaxf(m, sp[c]);
      float se = 0.f;
      for (int c = 0; c < C; ++c) se += __expf(sp[c] - m);
      conf = (lab < 0) ? 0.f : (m + __logf(se) - sp[lab]);
    }

    float cn = conf;
    if (lab > 0) {
      np_l++;
      cf_l += (double)conf;
      const float* pr = priors + (size_t)p * 6;
      const float* pl = locs + ((size_t)b * P + p) * 6;
      float ls = 0.f;
      for (int i = 0; i < 3; ++i) {
        const float c0 = (s_box[obj][i] + s_box[obj][i + 3]) * 0.5f;
        const float szb = s_box[obj][i + 3] - s_box[obj][i];
        const float g = (c0 - pr[i]) / (pr[i + 3] / 10.0f);
        const float g2 = logf(szb / pr[i + 3]) * 5.0f;
        ls += fabsf(pl[i] - g) + fabsf(pl[i + 3] - g2);
      }
      lc_l += (double)ls;
      cn = 0.f;
    }
    conf_neg[(size_t)b * P + p] = cn;
    atomicAdd(&s_hist[__float_as_uint(cn) >> 20], 1u);
  }

  __shared__ int r_np[256];
  __shared__ double r_c[256];
  __shared__ double r_l[256];
  r_np[tid] = np_l;
  r_c[tid] = cf_l;
  r_l[tid] = lc_l;
  __syncthreads();
  for (int s = 128; s > 0; s >>= 1) {
    if (tid < s) {
      r_np[tid] += r_np[tid + s];
      r_c[tid] += r_c[tid + s];
      r_l[tid] += r_l[tid + s];
    }
    __syncthreads();
  }
  if (tid == 0 && r_np[0] > 0) {
    atomicAdd(&n_pos[b], r_np[0]);
    atomicAdd(&pconf[b], r_c[0]);
    atomicAdd(&ploc[b], r_l[0]);
  }
  for (int i = tid; i < 4096; i += 256)
    if (s_hist[i]) atomicAdd(&hist0[(size_t)b * 4096 + i], s_hist[i]);
}

// Cooperative block-wide radix select over BINS bins (descending cumulative).
template <int BINS>
__device__ void block_select(const unsigned* __restrict__ h, int remk,
                             unsigned* s_scan, int* s_out, unsigned* sel,
                             int* remk_o) {
  constexpr int BPT = BINS / 256;
  const int t = threadIdx.x;
  if (t == 0) { s_out[0] = BINS - 1; s_out[1] = 0; }  // remk<=0 sentinel
  unsigned mb[BPT];
  unsigned s = 0;
#pragma unroll
  for (int i = 0; i < BPT; ++i) { mb[i] = h[t * BPT + i]; s += mb[i]; }
  unsigned incl = s;
  s_scan[t] = incl;
  __syncthreads();
  for (int off = 1; off < 256; off <<= 1) {
    const unsigned add = (t >= off) ? s_scan[t - off] : 0u;
    __syncthreads();
    incl += add;
    s_scan[t] = incl;
    __syncthreads();
  }
  const unsigned total = s_scan[255];
  const unsigned R = total - incl;  // count in bins above this thread's range
  if (remk > 0 && R < (unsigned)remk && R + s >= (unsigned)remk) {
    unsigned acc = R;
    int sel_i = t * BPT, rk = 0;
    bool done = false;
#pragma unroll
    for (int i = BPT - 1; i >= 0; --i) {
      if (!done && acc + mb[i] >= (unsigned)remk) {
        sel_i = t * BPT + i;
        rk = remk - (int)acc;
        done = true;
      }
      if (!done) acc += mb[i];
    }
    s_out[0] = sel_i;
    s_out[1] = rk;
  }
  __syncthreads();
  *sel = (unsigned)s_out[0];
  *remk_o = s_out[1];
  __syncthreads();
}

__global__ __launch_bounds__(256) void mbl_hist1(
    const float* __restrict__ conf_neg, const int* __restrict__ n_pos,
    const unsigned* __restrict__ hist0, unsigned* __restrict__ hist1, int P) {
  const int b = blockIdx.y;
  const int tid = threadIdx.x;
  __shared__ unsigned s_scan[256];
  __shared__ int s_out[2];
  __shared__ unsigned s_hist[4096];
  int K = 3 * n_pos[b];
  if (K > P) K = P;
  unsigned sel0;
  int rem0;
  block_select<4096>(hist0 + (size_t)b * 4096, K, s_scan, s_out, &sel0, &rem0);
  for (int i = tid; i < 4096; i += 256) s_hist[i] = 0u;
  __syncthreads();
  const float* row = conf_neg + (size_t)b * P;
  const int n4 = P >> 2;
  const int per = (n4 + (int)gridDim.x - 1) / (int)gridDim.x;
  const int s4 = blockIdx.x * per, e4 = min(s4 + per, n4);
  for (int i = s4 + tid; i < e4; i += 256) {
    const float4 v = ((const float4*)row)[i];
    unsigned u;
    u = __float_as_uint(v.x); if ((u >> 20) == sel0) atomicAdd(&s_hist[(u >> 8) & 4095u], 1u);
    u = __float_as_uint(v.y); if ((u >> 20) == sel0) atomicAdd(&s_hist[(u >> 8) & 4095u], 1u);
    u = __float_as_uint(v.z); if ((u >> 20) == sel0) atomicAdd(&s_hist[(u >> 8) & 4095u], 1u);
    u = __float_as_uint(v.w); if ((u >> 20) == sel0) atomicAdd(&s_hist[(u >> 8) & 4095u], 1u);
  }
  if (blockIdx.x == 0)
    for (int p = (n4 << 2) + tid; p < P; p += 256) {
      const unsigned u = __float_as_uint(row[p]);
      if ((u >> 20) == sel0) atomicAdd(&s_hist[(u >> 8) & 4095u], 1u);
    }
  __syncthreads();
  for (int i = tid; i < 4096; i += 256)
    if (s_hist[i]) atomicAdd(&hist1[(size_t)b * 4096 + i], s_hist[i]);
}

// Sum above 24-bit threshold; boundary bin approximated at its midpoint
// (relative error <= 2^-16 on few values -> ~1e-3 on the loss, thr 0.32).
// Last block finalizes outputs (completion counter + threadfence).
__global__ __launch_bounds__(256) void mbl_sum(
    const float* __restrict__ conf_neg, const int* __restrict__ n_pos,
    const unsigned* __restrict__ hist0, const unsigned* __restrict__ hist1,
    const double* __restrict__ pconf, const double* __restrict__ ploc,
    double* __restrict__ phard, unsigned* __restrict__ counter,
    int P, int B, float* __restrict__ out) {
  const int b = blockIdx.y;
  const int tid = threadIdx.x;
  __shared__ unsigned s_scan[256];
  __shared__ int s_out[2];
  int K = 3 * n_pos[b];
  if (K > P) K = P;
  unsigned sel0, sel1;
  int rem0, rem1;
  block_select<4096>(hist0 + (size_t)b * 4096, K, s_scan, s_out, &sel0, &rem0);
  block_select<4096>(hist1 + (size_t)b * 4096, rem0, s_scan, s_out, &sel1, &rem1);
  const unsigned pref24 = (sel0 << 12) | sel1;
  const unsigned tb = (pref24 << 8) | 0xFFu;  // strictly above boundary bin
  const float* row = conf_neg + (size_t)b * P;
  const int n4 = P >> 2;
  const int per = (n4 + (int)gridDim.x - 1) / (int)gridDim.x;
  const int s4 = blockIdx.x * per, e4 = min(s4 + per, n4);
  double local = 0.0;
  for (int i = s4 + tid; i < e4; i += 256) {
    const float4 v = ((const float4*)row)[i];
    if (__float_as_uint(v.x) > tb) local += (double)v.x;
    if (__float_as_uint(v.y) > tb) local += (double)v.y;
    if (__float_as_uint(v.z) > tb) local += (double)v.z;
    if (__float_as_uint(v.w) > tb) local += (double)v.w;
  }
  if (blockIdx.x == 0) {
    for (int p = (n4 << 2) + tid; p < P; p += 256) {
      const float v = row[p];
      if (__float_as_uint(v) > tb) local += (double)v;
    }
    if (tid == 0 && rem1 > 0)
      local += (double)rem1 * (double)__uint_as_float((pref24 << 8) | 0x80u);
  }
  __shared__ double red[256];
  red[tid] = local;
  __syncthreads();
  for (int s = 128; s > 0; s >>= 1) {
    if (tid < s) red[tid] += red[tid + s];
    __syncthreads();
  }
  if (tid == 0) {
    if (red[0] != 0.0) atomicAdd(&phard[b], red[0]);
    __threadfence();
    const unsigned done = atomicAdd(counter, 1u);
    if (done == gridDim.x * gridDim.y - 1) {
      double tp = 0.0, cs = 0.0, ls = 0.0, hs = 0.0;
      for (int i = 0; i < B; ++i) {
        tp += (double)n_pos[i];
        cs += pconf[i];
        ls += ploc[i];
        hs += atomicAdd(&phard[i], 0.0);
      }
      out[0] = (float)((hs + cs) / tp);
      out[1] = (float)(ls / (tp * 6.0));
    }
  }
}

extern "C" void kernel_launch(void* const* d_in, const int* in_sizes, int n_in,
                              void* d_out, int out_size, void* d_ws, size_t ws_size,
                              hipStream_t stream) {
  const float* locs = (const float*)d_in[0];
  const float* scores = (const float*)d_in[1];
  const float* boxes = (const float*)d_in[2];
  const int* labels = (const int*)d_in[3];
  const float* priors = (const float*)d_in[4];

  const long long sz_locs = (long long)in_sizes[0];
  const long long sz_scores = (long long)in_sizes[1];
  const long long sz_priors = (long long)in_sizes[4];
  const int P = (int)(sz_priors / 6);
  const int B = (int)(sz_locs / sz_priors);
  const int n_obj = in_sizes[3] / B;
  const int C = (int)(sz_scores * 6 / sz_locs);

  const int tile = 256 * MITEMS;
  const int nblk = (P + tile - 1) / tile;
  const int nobjT = (n_obj <= 16) ? 16 : ((n_obj <= 32) ? 32 : 64);

  char* ws = (char*)d_ws;
  size_t off = 0;
  double* pconf = (double*)(ws + off); off += (size_t)B * 8;
  double* ploc = (double*)(ws + off); off += (size_t)B * 8;
  double* phard = (double*)(ws + off); off += (size_t)B * 8;
  int* n_pos = (int*)(ws + off); off += ((size_t)B * 4 + 15) & ~(size_t)15;
  unsigned* counter = (unsigned*)(ws + off); off += 16;
  unsigned* hist0 = (unsigned*)(ws + off); off += (size_t)B * 4096 * 4;
  unsigned* hist1 = (unsigned*)(ws + off); off += (size_t)B * 4096 * 4;
  const size_t zero_bytes = off;  // multiple of 8
  float* conf_neg = (float*)(ws + off); off += ((size_t)B * P * 4 + 15) & ~(size_t)15;
  unsigned char* best_u8 = (unsigned char*)(ws + off);
  off += ((size_t)B * P + 15) & ~(size_t)15;
  unsigned long long* part_fo = (unsigned long long*)(ws + off);
  off += (size_t)B * nblk * nobjT * 8;
  (void)ws_size;

  const dim3 mgrid(nblk, B);
  const bool full = (P % tile) == 0;
  if (n_obj <= 16) {
    if (full) mbl_match<16, true><<<mgrid, 256, 0, stream>>>(boxes, priors, part_fo, best_u8, P, n_obj);
    else      mbl_match<16, false><<<mgrid, 256, 0, stream>>>(boxes, priors, part_fo, best_u8, P, n_obj);
  } else if (n_obj <= 32) {
    if (full) mbl_match<32, true><<<mgrid, 256, 0, stream>>>(boxes, priors, part_fo, best_u8, P, n_obj);
    else      mbl_match<32, false><<<mgrid, 256, 0, stream>>>(boxes, priors, part_fo, best_u8, P, n_obj);
  } else {
    if (full) mbl_match<64, true><<<mgrid, 256, 0, stream>>>(boxes, priors, part_fo, best_u8, P, n_obj);
    else      mbl_match<64, false><<<mgrid, 256, 0, stream>>>(boxes, priors, part_fo, best_u8, P, n_obj);
  }

  mbl_reduce_fo<<<B, 256, 0, stream>>>(part_fo, best_u8, (unsigned long long*)d_ws,
                                       (int)(zero_bytes / 8), nblk, n_obj, nobjT, P);

  const dim3 lgrid(LB, B);
  if (C == 2)
    mbl_loss<2><<<lgrid, 256, 0, stream>>>(locs, scores, boxes, labels, priors,
                                           best_u8, conf_neg, hist0, n_pos, pconf, ploc,
                                           P, n_obj, C);
  else
    mbl_loss<0><<<lgrid, 256, 0, stream>>>(locs, scores, boxes, labels, priors,
                                           best_u8, conf_neg, hist0, n_pos, pconf, ploc,
                                           P, n_obj, C);

  mbl_hist1<<<lgrid, 256, 0, stream>>>(conf_neg, n_pos, hist0, hist1, P);
  mbl_sum<<<lgrid, 256, 0, stream>>>(conf_neg, n_pos, hist0, hist1, pconf, ploc,
                                     phard, counter, P, B, (float*)d_out);
}